// Round 15
// baseline (105.030 us; speedup 1.0000x reference)
//
#include <hip/hip_runtime.h>
#include <hip/hip_fp16.h>

typedef _Float16 h8 __attribute__((ext_vector_type(8)));
typedef _Float16 h4 __attribute__((ext_vector_type(4)));
typedef float f32x4 __attribute__((ext_vector_type(4)));
typedef float f32x16 __attribute__((ext_vector_type(16)));
typedef unsigned int u32x2 __attribute__((ext_vector_type(2)));
typedef unsigned int u32x4 __attribute__((ext_vector_type(4)));

#define MFMA16(a, b, c) __builtin_amdgcn_mfma_f32_16x16x32_f16((a), (b), (c), 0, 0, 0)
#define MFMA32(a, b, c) __builtin_amdgcn_mfma_f32_32x32x16_f16((a), (b), (c), 0, 0, 0)

static constexpr int MM = 2048, NN = 2048, DD = 128;
static constexpr int NT = 16;  // 16 key tiles of 128
static constexpr size_t KV_IMG = (size_t)16 * 16 * 32768;  // 8 MiB per tensor
static constexpr size_t IND_IMG = 65536;                   // fp16[32768]
static constexpr size_t WS_NEED = 2 * KV_IMG + IND_IMG + 32768 * 4;

static constexpr float C1 = 0.25503487f;              // 2*log2(e)/sqrt(128)
static constexpr float C2 = 28.853900817779268f;      // 20*log2(e)
static constexpr float CVALID = 14.426950408889634f;  // 10*log2(e)
static constexpr float CMASK = -1.0e30f;

__device__ inline void glds16(const void* g, void* l) {
  __builtin_amdgcn_global_load_lds(
      (const __attribute__((address_space(1))) void*)g,
      (__attribute__((address_space(3))) void*)l, 16, 0, 0);
}

// ---------------- mask -> per-key bias (fallback path only) ----------------
__global__ __launch_bounds__(256) void prep_bias(const void* __restrict__ mraw,
                                                 float* __restrict__ biasC) {
  const int tid = threadIdx.x;
  const unsigned int* mw = (const unsigned int*)mraw;
  const unsigned char* mby = (const unsigned char*)mraw;
  int okW = 1;
  for (int w = tid; w < 8192; w += 256) {
    unsigned int v = mw[w];
    okW &= (v == 0u || v == 1u || v == 0x3f800000u) ? 1 : 0;
  }
  __shared__ int sW;
  if (tid == 0) sW = 1;
  __syncthreads();
  if (!okW) atomicAnd(&sW, 0);
  __syncthreads();
  const int i = blockIdx.x * 256 + tid;
  bool masked = sW ? (mw[i] != 0u) : (mby[i] != 0);
  biasC[i] = masked ? CMASK : CVALID;
}

// ---------------- fused pre-pass (round-14, verbatim) ----------------------
// 128-key tile (32KB each):
//   K: byte = key*256 + ((16*o) ^ ((key&7)<<4)), o = d/8; value K*C1.
//   V: byte = d*256 + ((g*16) ^ ((d&7)<<4)), g = key/8; masked cols zeroed.
// V blocks detect the mask dtype inline (global 32KB scan) and write ind.
__global__ __launch_bounds__(256) void prep_all(
    const float* __restrict__ K, const float* __restrict__ V,
    const void* __restrict__ mraw, unsigned char* __restrict__ kimg,
    unsigned char* __restrict__ vimg, _Float16* __restrict__ ind) {
  const int id = blockIdx.x;
  const int tid = threadIdx.x;
  if (id < 512) {  // ---- K ----
    const int bt = id;  // 64-key granule
    const float* src = K + (size_t)bt * 64 * DD;
    unsigned char* dst = kimg + (size_t)(bt >> 1) * 32768 + (bt & 1) * 16384;
#pragma unroll
    for (int it = 0; it < 4; ++it) {
      const int key = (tid >> 4) + 16 * it;  // 0..63 local
      const int o = tid & 15;
      f32x4 a = *(const f32x4*)(src + key * DD + 8 * o);
      f32x4 c = *(const f32x4*)(src + key * DD + 8 * o + 4);
      h8 hv;
#pragma unroll
      for (int j = 0; j < 4; ++j) {
        hv[j] = (_Float16)(a[j] * C1);  // fold C1 into K
        hv[j + 4] = (_Float16)(c[j] * C1);
      }
      *(h8*)(dst + key * 256 + ((16 * o) ^ ((key & 7) << 4))) = hv;
    }
  } else {  // ---- V (inline mask detect + zero + ind write + transpose) ----
    const int bt = id - 512;
    const unsigned int* mw = (const unsigned int*)mraw;
    const unsigned char* mby = (const unsigned char*)mraw;
    int okW = 1;  // word-typed (i32 0/1 or f32 0.0/1.0)?
    for (int w = tid; w < 8192; w += 256) {
      unsigned int v = mw[w];
      okW &= (v == 0u || v == 1u || v == 0x3f800000u) ? 1 : 0;
    }
    __shared__ int sW;
    __shared__ float sip[64];
    if (tid == 0) sW = 1;
    __syncthreads();
    if (!okW) atomicAnd(&sW, 0);
    __syncthreads();
    if (tid < 64) {
      const int gk = bt * 64 + tid;
      bool masked = sW ? (mw[gk] != 0u) : (mby[gk] != 0);
      sip[tid] = masked ? 0.0f : 1.0f;
      ind[gk] = masked ? (_Float16)0.0f : (_Float16)1.0f;
    }
    __syncthreads();
    const float* src = V + (size_t)bt * 64 * DD;
    unsigned char* dst = vimg + (size_t)(bt >> 1) * 32768;
    const int d = tid & 127;
    const int half = tid >> 7;
#pragma unroll
    for (int ki = 0; ki < 4; ++ki) {
      const int koct = half * 4 + ki;  // 0..7 local key-octet
      h8 w;
#pragma unroll
      for (int q = 0; q < 8; ++q)
        w[q] = (_Float16)(src[(8 * koct + q) * DD + d] * sip[8 * koct + q]);
      const int g = (bt & 1) * 8 + koct;
      *(h8*)(dst + d * 256 + ((g * 16) ^ ((d & 7) << 4))) = w;
    }
  }
}

// ---------------- fused attention: shared-fragment 64q/wave, 2 waves/SIMD --
// 256 blocks x 512 thr (1/CU, 8 waves = 2/SIMD). Block = 128 q-rows;
// 8 waves = 2 qg(64q) x 4 kh(32-key quarters). Each K/V fragment is read
// from LDS ONCE and feeds TWO q-group MFMAs: 18 b128 reads/wave/tile vs the
// champion's 36, at identical occupancy, MFMA count, softmax and staging.
__global__ __launch_bounds__(512, 2) void attn_main(
    const float* __restrict__ Qg, const unsigned char* __restrict__ kimg,
    const unsigned char* __restrict__ vimg, const _Float16* __restrict__ indg,
    float* __restrict__ out) {
  __shared__ __align__(16) unsigned char smem[137216];
  // [0,65536)        buf0 {K 32K, V^T 32K}
  // [65536,131072)   buf1
  // [131072,135168)  indicator (whole batch: 2048 keys fp16)
  // [135168,137216)  rsH[4][128] f32
  // epilogue: bufA=[0,65536) (kh0+kh1), bufB=[65536,131072) (kh2+kh3),
  //           both f32[128][128] with granule ^= ((row&31)<<4)
  const int tid = threadIdx.x;
  const int lane = tid & 63;
  const int wv = tid >> 6;   // 0..7
  const int l31 = lane & 31;
  const int hp = lane >> 5;
  const int qg = wv >> 2;    // 0..1: 64-row group
  const int kh = wv & 3;     // 0..3: 32-key quarter
  const int bid = blockIdx.x;
  const int b = 2 * (bid & 7) + (bid >> 7);  // 2 batches per XCD
  const int mt = (bid >> 3) & 15;
  const int m0 = mt * 128 + qg * 64;

  // ---- Q B-frags fp16 (C1 folded into K image): col=q=l31, k=16st+8hp+j ----
  h8 qa[2][8];
#pragma unroll
  for (int qgrp = 0; qgrp < 2; ++qgrp) {
    const float* qr = Qg + ((size_t)b * MM + m0 + qgrp * 32 + l31) * DD;
#pragma unroll
    for (int st = 0; st < 8; ++st) {
      const int d0 = 16 * st + 8 * hp;
      f32x4 a = *(const f32x4*)(qr + d0);
      f32x4 c = *(const f32x4*)(qr + d0 + 4);
      h8 hi;
#pragma unroll
      for (int j = 0; j < 4; ++j) {
        hi[j] = (_Float16)a[j];
        hi[j + 4] = (_Float16)c[j];
      }
      qa[qgrp][st] = hi;
    }
  }

  f32x16 oacc[2][4];  // [qgrp][dc]: O^T[32dc + dd(reg,hp)][q=l31]
#pragma unroll
  for (int qgrp = 0; qgrp < 2; ++qgrp)
#pragma unroll
    for (int dc = 0; dc < 4; ++dc)
#pragma unroll
      for (int j = 0; j < 16; ++j) oacc[qgrp][dc][j] = 0.f;
  f32x16 rsacc[2];  // rowsum via indicator MFMA (all regs identical)
#pragma unroll
  for (int qgrp = 0; qgrp < 2; ++qgrp)
#pragma unroll
    for (int j = 0; j < 16; ++j) rsacc[qgrp][j] = 0.f;

  const unsigned char* kib = kimg + (size_t)b * 16 * 32768;
  const unsigned char* vib = vimg + (size_t)b * 16 * 32768;
  unsigned char* sind = smem + 131072;

  // ---- prologue: stage tile 0 + whole-batch indicator (champion schedule) --
#pragma unroll
  for (int i = 0; i < 4; ++i) {
    const int off = wv * 4096 + i * 1024;
    glds16(kib + off + lane * 16, smem + off);
    glds16(vib + off + lane * 16, smem + 32768 + off);
  }
  if (wv < 4)
    glds16((const unsigned char*)indg + (size_t)b * 4096 + wv * 1024 + lane * 16,
           sind + wv * 1024);
  __syncthreads();

  const int ksw = (l31 & 7) << 4;          // key&7 == l31&7; also d&7 == l31&7
  const int krow = (32 * kh + l31) << 8;   // this wave's key row

  for (int tn = 0; tn < NT; ++tn) {
    const unsigned char* kbuf = smem + (tn & 1) * 65536;
    const unsigned char* vbuf = kbuf + 32768;
    if (tn + 1 < NT) {
      unsigned char* nbuf = smem + ((tn + 1) & 1) * 65536;
      const unsigned char* ks = kib + (size_t)(tn + 1) * 32768;
      const unsigned char* vs = vib + (size_t)(tn + 1) * 32768;
#pragma unroll
      for (int i = 0; i < 4; ++i) {
        const int off = wv * 4096 + i * 1024;
        glds16(ks + off + lane * 16, nbuf + off);
        glds16(vs + off + lane * 16, nbuf + 32768 + off);
      }
    }

    // ---- QK^T swapped: each kf feeds BOTH q-groups (8 loads, 16 MFMA) ----
    f32x16 s[2];
#pragma unroll
    for (int j = 0; j < 16; ++j) { s[0][j] = 0.f; s[1][j] = 0.f; }
    __builtin_amdgcn_s_setprio(1);
#pragma unroll
    for (int st = 0; st < 8; ++st) {
      h8 kf = *(const h8*)(kbuf + krow + ((32 * st + 16 * hp) ^ ksw));
      s[0] = MFMA32(kf, qa[0][st], s[0]);
      s[1] = MFMA32(kf, qa[1][st], s[1]);
    }
    __builtin_amdgcn_s_setprio(0);

    // ---- maskless clipped softmax, fully in-register (per q-group) ----
    h8 pb[2][2];  // B-frags, keys 32kh + 16ks + 8hp + j
#pragma unroll
    for (int qgrp = 0; qgrp < 2; ++qgrp) {
      unsigned pkA[4], pkB[4];
#pragma unroll
      for (int jq = 0; jq < 4; ++jq) {
        float p[4];
#pragma unroll
        for (int i = 0; i < 4; ++i) {
          const float u = __builtin_amdgcn_exp2f(s[qgrp][4 * jq + i]);
          p[i] = __builtin_amdgcn_exp2f(
              fmaf(-C2, __builtin_amdgcn_rcpf(u + 1.0f), CVALID));
        }
        pkA[jq] = __builtin_bit_cast(unsigned,
                                     __builtin_amdgcn_cvt_pkrtz(p[0], p[1]));
        pkB[jq] = __builtin_bit_cast(unsigned,
                                     __builtin_amdgcn_cvt_pkrtz(p[2], p[3]));
      }
#pragma unroll
      for (int ks = 0; ks < 2; ++ks) {
        u32x2 sa = __builtin_amdgcn_permlane32_swap(pkA[2 * ks],
                                                    pkA[2 * ks + 1], false,
                                                    false);
        u32x2 sb = __builtin_amdgcn_permlane32_swap(pkB[2 * ks],
                                                    pkB[2 * ks + 1], false,
                                                    false);
        u32x4 w = {sa[0], sb[0], sa[1], sb[1]};
        pb[qgrp][ks] = __builtin_bit_cast(h8, w);
      }
    }

    // ---- rowsum (shared ia) + P.V (shared vf) into persistent C regs ----
    __builtin_amdgcn_s_setprio(1);
#pragma unroll
    for (int ks = 0; ks < 2; ++ks) {
      h8 ia = *(const h8*)(sind + tn * 256 + 64 * kh + 32 * ks + 16 * hp);
      rsacc[0] = MFMA32(ia, pb[0][ks], rsacc[0]);
      rsacc[1] = MFMA32(ia, pb[1][ks], rsacc[1]);
    }
#pragma unroll
    for (int dc = 0; dc < 4; ++dc) {
      const int vrow = (32 * dc + l31) << 8;
#pragma unroll
      for (int ks = 0; ks < 2; ++ks) {
        h8 vf = *(const h8*)(vbuf + vrow +
                             ((64 * kh + 32 * ks + 16 * hp) ^ ksw));
        oacc[0][dc] = MFMA32(vf, pb[0][ks], oacc[0][dc]);
        oacc[1][dc] = MFMA32(vf, pb[1][ks], oacc[1][dc]);
      }
    }
    __builtin_amdgcn_s_setprio(0);
    __syncthreads();  // next tile resident; this buf free
  }

  // ---- epilogue: merge 4 key-quarter partials, normalize, store ----
  unsigned char* bufA = smem;           // kh0 + kh1
  unsigned char* bufB = smem + 65536;   // kh2 + kh3
  float* rsH = (float*)(smem + 135168); // [4][128]
#pragma unroll
  for (int qgrp = 0; qgrp < 2; ++qgrp) {
    const int row = qg * 64 + qgrp * 32 + l31;
    if (hp == 0) rsH[kh * 128 + row] = rsacc[qgrp][0];
  }
  if (kh == 1 || kh == 3) {
    unsigned char* buf = (kh == 1) ? bufA : bufB;
#pragma unroll
    for (int qgrp = 0; qgrp < 2; ++qgrp) {
      const int row = qg * 64 + qgrp * 32 + l31;
#pragma unroll
      for (int dc = 0; dc < 4; ++dc)
#pragma unroll
        for (int jq = 0; jq < 4; ++jq) {
          f32x4 v = {oacc[qgrp][dc][4 * jq + 0], oacc[qgrp][dc][4 * jq + 1],
                     oacc[qgrp][dc][4 * jq + 2], oacc[qgrp][dc][4 * jq + 3]};
          const int dbyte = (32 * dc + 8 * jq + 4 * hp) * 4;
          *(f32x4*)(buf + row * 512 + (dbyte ^ ((row & 31) << 4))) = v;
        }
    }
  }
  __syncthreads();
  if (kh == 0 || kh == 2) {
    unsigned char* buf = (kh == 0) ? bufA : bufB;
#pragma unroll
    for (int qgrp = 0; qgrp < 2; ++qgrp) {
      const int row = qg * 64 + qgrp * 32 + l31;
#pragma unroll
      for (int dc = 0; dc < 4; ++dc)
#pragma unroll
        for (int jq = 0; jq < 4; ++jq) {
          const int dbyte = (32 * dc + 8 * jq + 4 * hp) * 4;
          float* pp = (float*)(buf + row * 512 + (dbyte ^ ((row & 31) << 4)));
          f32x4 v = *(const f32x4*)pp;
          v[0] += oacc[qgrp][dc][4 * jq + 0];
          v[1] += oacc[qgrp][dc][4 * jq + 1];
          v[2] += oacc[qgrp][dc][4 * jq + 2];
          v[3] += oacc[qgrp][dc][4 * jq + 3];
          *(f32x4*)pp = v;
        }
    }
  }
  __syncthreads();
  float* ob = out + ((size_t)b * MM + mt * 128) * DD;
#pragma unroll
  for (int it = 0; it < 8; ++it) {
    const int byte = it * 8192 + tid * 16;
    const int r2 = byte >> 9;
    const int g16 = byte & 511;
    const int off = r2 * 512 + (g16 ^ ((r2 & 31) << 4));
    f32x4 a = *(const f32x4*)(bufA + off);
    f32x4 c = *(const f32x4*)(bufB + off);
    const float tot =
        rsH[r2] + rsH[128 + r2] + rsH[256 + r2] + rsH[384 + r2];
    const float inv = __builtin_amdgcn_rcpf(tot);
    f32x4 v = {(a[0] + c[0]) * inv, (a[1] + c[1]) * inv, (a[2] + c[2]) * inv,
               (a[3] + c[3]) * inv};
    *(f32x4*)((unsigned char*)ob + byte) = v;
  }
}

// ---------------- fallback (round-3 path) if ws too small ----------------
__global__ __launch_bounds__(256, 2) void attn_fallback(
    const float* __restrict__ Qg, const float* __restrict__ Kg,
    const float* __restrict__ Vg, const float* __restrict__ biasC,
    float* __restrict__ out) {
  __shared__ __align__(16) unsigned char smem[51456];
  const int tid = threadIdx.x;
  const int lane = tid & 63;
  const int wv = tid >> 6;
  const int r = lane & 15;
  const int g = lane >> 4;
  const int rw = wv >> 1;
  const int h = wv & 1;
  const int b = blockIdx.x >> 5;
  const int mt = blockIdx.x & 31;
  const int m0 = mt * 64 + rw * 32;

  float* blds = (float*)(smem + 43264);
  {
    const float* cb = biasC + b * NN;
#pragma unroll
    for (int i = 0; i < 8; ++i) blds[tid + 256 * i] = cb[tid + 256 * i];
  }
  h8 qh[2][4];
  {
    const float* qb = Qg + ((size_t)b * MM + m0) * DD;
#pragma unroll
    for (int rf = 0; rf < 2; ++rf) {
      const float* qr = qb + (16 * rf + r) * DD;
#pragma unroll
      for (int t = 0; t < 4; ++t) {
        f32x4 a = *(const f32x4*)(qr + 32 * t + 8 * g);
        f32x4 c = *(const f32x4*)(qr + 32 * t + 8 * g + 4);
        h8 hi;
#pragma unroll
        for (int j = 0; j < 4; ++j) {
          hi[j] = (_Float16)a[j];
          hi[j + 4] = (_Float16)c[j];
        }
        qh[rf][t] = hi;
      }
    }
  }
  f32x4 acc[2][8];
#pragma unroll
  for (int rf = 0; rf < 2; ++rf)
#pragma unroll
    for (int cd = 0; cd < 8; ++cd) acc[rf][cd] = (f32x4){0.f, 0.f, 0.f, 0.f};
  float rs[2][4] = {{0.f, 0.f, 0.f, 0.f}, {0.f, 0.f, 0.f, 0.f}};
  const float* kb = Kg + (size_t)b * NN * DD;
  const float* vbp = Vg + (size_t)b * NN * DD;
  _Float16* plds = (_Float16*)(smem + 32768 + wv * 2560);
  const int bk0 = tid >> 5, bd0 = tid & 31;
  const int bk1 = (256 + tid) >> 5, bd1 = tid & 31;
  f32x4 kpre[8], vpre[8];
#pragma unroll
  for (int i = 0; i < 8; ++i) kpre[i] = *(const f32x4*)(kb + i * 1024 + tid * 4);
#pragma unroll
  for (int q = 0; q < 4; ++q) {
    vpre[q] = *(const f32x4*)(vbp + (4 * bk0 + q) * DD + 4 * bd0);
    vpre[4 + q] = *(const f32x4*)(vbp + (4 * bk1 + q) * DD + 4 * bd1);
  }
  for (int tn = 0; tn < 32; ++tn) {
#pragma unroll
    for (int i = 0; i < 8; ++i) {
      const int flat = i * 1024 + tid * 4;
      const int kkey = flat >> 7;
      const int d0 = flat & 127;
      h4 hv;
#pragma unroll
      for (int j = 0; j < 4; ++j) hv[j] = (_Float16)kpre[i][j];
      *(h4*)(smem + (kkey << 8) + ((d0 << 1) ^ ((kkey & 7) << 4))) = hv;
    }
#pragma unroll
    for (int it = 0; it < 2; ++it) {
      const int bk = it ? bk1 : bk0;
      const int bd = it ? bd1 : bd0;
#pragma unroll
      for (int p = 0; p < 4; ++p) {
        h4 w;
#pragma unroll
        for (int q = 0; q < 4; ++q) w[q] = (_Float16)vpre[it * 4 + q][p];
        const int d = 4 * bd + p;
        *(h4*)(smem + 16384 + (d << 7) +
               ((bk << 3) ^ (((d >> 1) & 7) << 4))) = w;
      }
    }
    if (tn + 1 < 32) {
      const float* ks = kb + (tn + 1) * 64 * DD;
      const float* vs = vbp + (tn + 1) * 64 * DD;
#pragma unroll
      for (int i = 0; i < 8; ++i) kpre[i] = *(const f32x4*)(ks + i * 1024 + tid * 4);
#pragma unroll
      for (int q = 0; q < 4; ++q) {
        vpre[q] = *(const f32x4*)(vs + (4 * bk0 + q) * DD + 4 * bd0);
        vpre[4 + q] = *(const f32x4*)(vs + (4 * bk1 + q) * DD + 4 * bd1);
      }
    }
    __syncthreads();
#pragma unroll
    for (int c = 0; c < 2; ++c) {
      f32x4 S0 = {0.f, 0.f, 0.f, 0.f}, S1 = {0.f, 0.f, 0.f, 0.f};
      const int kkey = h * 32 + 16 * c + r;
      const int krow = kkey << 8;
      const int ksw = (kkey & 7) << 4;
#pragma unroll
      for (int t = 0; t < 4; ++t) {
        h8 kf = *(const h8*)(smem + krow + ((64 * t + 16 * g) ^ ksw));
        S0 = MFMA16(qh[0][t], kf, S0);
        S1 = MFMA16(qh[1][t], kf, S1);
      }
      const float Cc = blds[tn * 64 + kkey];
#pragma unroll
      for (int j = 0; j < 4; ++j) {
        float u0 = __builtin_amdgcn_exp2f(S0[j] * C1);
        float p0 = __builtin_amdgcn_exp2f(
            fmaf(-C2, __builtin_amdgcn_rcpf(u0 + 1.0f), Cc));
        rs[0][j] += p0;
        plds[(4 * g + j) * 40 + 16 * c + r] = (_Float16)p0;
        float u1 = __builtin_amdgcn_exp2f(S1[j] * C1);
        float p1 = __builtin_amdgcn_exp2f(
            fmaf(-C2, __builtin_amdgcn_rcpf(u1 + 1.0f), Cc));
        rs[1][j] += p1;
        plds[(16 + 4 * g + j) * 40 + 16 * c + r] = (_Float16)p1;
      }
    }
    h8 a0 = *(const h8*)((unsigned char*)plds + r * 80 + 16 * g);
    h8 a1 = *(const h8*)((unsigned char*)plds + (16 + r) * 80 + 16 * g);
#pragma unroll
    for (int cd = 0; cd < 8; ++cd) {
      const int d = 16 * cd + r;
      h8 vf = *(const h8*)(smem + 16384 + (d << 7) +
                           ((64 * h + 16 * g) ^ (((d >> 1) & 7) << 4)));
      acc[0][cd] = MFMA16(a0, vf, acc[0][cd]);
      acc[1][cd] = MFMA16(a1, vf, acc[1][cd]);
    }
    __syncthreads();
  }
#pragma unroll
  for (int rf = 0; rf < 2; ++rf)
#pragma unroll
    for (int j = 0; j < 4; ++j) {
      float v = rs[rf][j];
      v += __shfl_xor(v, 1);
      v += __shfl_xor(v, 2);
      v += __shfl_xor(v, 4);
      v += __shfl_xor(v, 8);
      rs[rf][j] = v;
    }
  float* olds = (float*)smem;
  float* rslds = (float*)(smem + 43008);
  if (h == 1) {
    float* my = olds + rw * 4096;
#pragma unroll
    for (int rf = 0; rf < 2; ++rf)
#pragma unroll
      for (int cd = 0; cd < 8; ++cd)
#pragma unroll
        for (int j = 0; j < 4; ++j)
          my[(16 * rf + 4 * g + j) * 128 + 16 * cd + r] = acc[rf][cd][j];
    if (r == 0) {
#pragma unroll
      for (int rf = 0; rf < 2; ++rf)
#pragma unroll
        for (int j = 0; j < 4; ++j)
          rslds[rw * 32 + 16 * rf + 4 * g + j] = rs[rf][j];
    }
  }
  __syncthreads();
  if (h == 0) {
    const float* ot = olds + rw * 4096;
    float* ob = out + ((size_t)b * MM + m0) * DD;
#pragma unroll
    for (int rf = 0; rf < 2; ++rf)
#pragma unroll
      for (int j = 0; j < 4; ++j) {
        const int rl = 16 * rf + 4 * g + j;
        const float tot = rs[rf][j] + rslds[rw * 32 + rl];
        const float inv = __builtin_amdgcn_rcpf(tot);
#pragma unroll
        for (int cd = 0; cd < 8; ++cd) {
          float v = acc[rf][cd][j] + ot[rl * 128 + 16 * cd + r];
          ob[rl * DD + 16 * cd + r] = v * inv;
        }
      }
  }
}

extern "C" void kernel_launch(void* const* d_in, const int* in_sizes, int n_in,
                              void* d_out, int out_size, void* d_ws, size_t ws_size,
                              hipStream_t stream) {
  const float* Q = (const float*)d_in[0];
  const float* K = (const float*)d_in[1];
  const float* V = (const float*)d_in[2];
  const void* mask = d_in[3];
  float* out = (float*)d_out;
  if (ws_size >= WS_NEED) {
    unsigned char* kimg = (unsigned char*)d_ws;
    unsigned char* vimg = kimg + KV_IMG;
    _Float16* ind = (_Float16*)(vimg + KV_IMG);
    prep_all<<<dim3(1024), dim3(256), 0, stream>>>(K, V, mask, kimg, vimg, ind);
    attn_main<<<dim3(256), dim3(512), 0, stream>>>(Q, kimg, vimg, ind, out);
  } else {
    float* biasC = (float*)d_ws;  // 32768 floats
    prep_bias<<<dim3(128), dim3(256), 0, stream>>>(mask, biasC);
    attn_fallback<<<dim3(512), dim3(256), 0, stream>>>(Q, K, V, biasC, out);
  }
}

// Round 16
// 72.887 us; speedup vs baseline: 1.4410x; 1.4410x over previous
//
#include <hip/hip_runtime.h>
#include <hip/hip_fp16.h>

typedef _Float16 h8 __attribute__((ext_vector_type(8)));
typedef _Float16 h4 __attribute__((ext_vector_type(4)));
typedef float f32x4 __attribute__((ext_vector_type(4)));
typedef float f32x16 __attribute__((ext_vector_type(16)));
typedef unsigned int u32x2 __attribute__((ext_vector_type(2)));
typedef unsigned int u32x4 __attribute__((ext_vector_type(4)));

#define MFMA16(a, b, c) __builtin_amdgcn_mfma_f32_16x16x32_f16((a), (b), (c), 0, 0, 0)
#define MFMA32(a, b, c) __builtin_amdgcn_mfma_f32_32x32x16_f16((a), (b), (c), 0, 0, 0)

static constexpr int MM = 2048, NN = 2048, DD = 128;
static constexpr int NT = 16;  // 16 key tiles of 128
static constexpr size_t KV_IMG = (size_t)16 * 16 * 32768;  // 8 MiB per tensor
static constexpr size_t IND_IMG = 65536;                   // fp16[32768]
static constexpr size_t WS_NEED = 2 * KV_IMG + IND_IMG + 32768 * 4;

static constexpr float C1 = 0.25503487f;              // 2*log2(e)/sqrt(128)
static constexpr float C2 = 28.853900817779268f;      // 20*log2(e)
static constexpr float CVALID = 14.426950408889634f;  // 10*log2(e)
static constexpr float CMASK = -1.0e30f;

__device__ inline void glds16(const void* g, void* l) {
  __builtin_amdgcn_global_load_lds(
      (const __attribute__((address_space(1))) void*)g,
      (__attribute__((address_space(3))) void*)l, 16, 0, 0);
}

// ---------------- mask -> per-key bias (fallback path only) ----------------
__global__ __launch_bounds__(256) void prep_bias(const void* __restrict__ mraw,
                                                 float* __restrict__ biasC) {
  const int tid = threadIdx.x;
  const unsigned int* mw = (const unsigned int*)mraw;
  const unsigned char* mby = (const unsigned char*)mraw;
  int okW = 1;
  for (int w = tid; w < 8192; w += 256) {
    unsigned int v = mw[w];
    okW &= (v == 0u || v == 1u || v == 0x3f800000u) ? 1 : 0;
  }
  __shared__ int sW;
  if (tid == 0) sW = 1;
  __syncthreads();
  if (!okW) atomicAnd(&sW, 0);
  __syncthreads();
  const int i = blockIdx.x * 256 + tid;
  bool masked = sW ? (mw[i] != 0u) : (mby[i] != 0);
  biasC[i] = masked ? CMASK : CVALID;
}

// ---------------- fused pre-pass: K,V -> fp16 LDS-images, mask -> ind ------
// 128-key tile (32KB each):
//   K: byte = key*256 + ((16*o) ^ ((key&7)<<4)), o = d/8; value K*C1.
//   V: byte = d*256 + ((g*16) ^ ((d&7)<<4)), g = key/8; masked cols zeroed.
// V blocks detect the mask dtype inline (global 32KB scan) and write ind.
__global__ __launch_bounds__(256) void prep_all(
    const float* __restrict__ K, const float* __restrict__ V,
    const void* __restrict__ mraw, unsigned char* __restrict__ kimg,
    unsigned char* __restrict__ vimg, _Float16* __restrict__ ind) {
  const int id = blockIdx.x;
  const int tid = threadIdx.x;
  if (id < 512) {  // ---- K ----
    const int bt = id;  // 64-key granule
    const float* src = K + (size_t)bt * 64 * DD;
    unsigned char* dst = kimg + (size_t)(bt >> 1) * 32768 + (bt & 1) * 16384;
#pragma unroll
    for (int it = 0; it < 4; ++it) {
      const int key = (tid >> 4) + 16 * it;  // 0..63 local
      const int o = tid & 15;
      f32x4 a = *(const f32x4*)(src + key * DD + 8 * o);
      f32x4 c = *(const f32x4*)(src + key * DD + 8 * o + 4);
      h8 hv;
#pragma unroll
      for (int j = 0; j < 4; ++j) {
        hv[j] = (_Float16)(a[j] * C1);  // fold C1 into K
        hv[j + 4] = (_Float16)(c[j] * C1);
      }
      *(h8*)(dst + key * 256 + ((16 * o) ^ ((key & 7) << 4))) = hv;
    }
  } else {  // ---- V (inline mask detect + zero + ind write + transpose) ----
    const int bt = id - 512;
    const unsigned int* mw = (const unsigned int*)mraw;
    const unsigned char* mby = (const unsigned char*)mraw;
    int okW = 1;  // word-typed (i32 0/1 or f32 0.0/1.0)?
    for (int w = tid; w < 8192; w += 256) {
      unsigned int v = mw[w];
      okW &= (v == 0u || v == 1u || v == 0x3f800000u) ? 1 : 0;
    }
    __shared__ int sW;
    __shared__ float sip[64];
    if (tid == 0) sW = 1;
    __syncthreads();
    if (!okW) atomicAnd(&sW, 0);
    __syncthreads();
    if (tid < 64) {
      const int gk = bt * 64 + tid;
      bool masked = sW ? (mw[gk] != 0u) : (mby[gk] != 0);
      sip[tid] = masked ? 0.0f : 1.0f;
      ind[gk] = masked ? (_Float16)0.0f : (_Float16)1.0f;
    }
    __syncthreads();
    const float* src = V + (size_t)bt * 64 * DD;
    unsigned char* dst = vimg + (size_t)(bt >> 1) * 32768;
    const int d = tid & 127;
    const int half = tid >> 7;
#pragma unroll
    for (int ki = 0; ki < 4; ++ki) {
      const int koct = half * 4 + ki;  // 0..7 local key-octet
      h8 w;
#pragma unroll
      for (int q = 0; q < 8; ++q)
        w[q] = (_Float16)(src[(8 * koct + q) * DD + d] * sip[8 * koct + q]);
      const int g = (bt & 1) * 8 + koct;
      *(h8*)(dst + d * 256 + ((g * 16) ^ ((d & 7) << 4))) = w;
    }
  }
}

// ---------------- fused attention (round-8 champion, verbatim) -------------
// 256 blocks x 512 thr (1/CU). Block = 128 q-rows; 8 waves = 4 qg x 2 kh.
// Wave: 32q x 64 keys per 128-key tile. Softmax has ZERO mask logic (mask is
// folded into zeroed V columns + indicator row); rowsum via indicator MFMA.
__global__ __launch_bounds__(512, 1) void attn_main(
    const float* __restrict__ Qg, const unsigned char* __restrict__ kimg,
    const unsigned char* __restrict__ vimg, const _Float16* __restrict__ indg,
    float* __restrict__ out) {
  __shared__ __align__(16) unsigned char smem[135680];
  // [0,65536)        buf0 {K 32K, V^T 32K}
  // [65536,131072)   buf1
  // [131072,135168)  indicator (whole batch: 2048 keys fp16 = 4KB)
  // [135168,135680)  rs1 (128 f32)
  // epilogue: [0,65536) reused as olds f32[128][128], XOR-swizzled granules
  const int tid = threadIdx.x;
  const int lane = tid & 63;
  const int wv = tid >> 6;   // 0..7
  const int l31 = lane & 31;
  const int hp = lane >> 5;
  const int qg = wv >> 1;    // row group (32 rows)
  const int h = wv & 1;      // key half (64 keys)
  const int bid = blockIdx.x;
  const int b = 2 * (bid & 7) + (bid >> 7);  // 2 batches per XCD
  const int mt = (bid >> 3) & 15;
  const int m0 = mt * 128 + qg * 32;

  // ---- Q B-frags fp16 (x C1 folded into K image): col=q=l31, k=16st+8hp+j
  h8 qa[8];
  {
    const float* qr = Qg + ((size_t)b * MM + m0 + l31) * DD;
#pragma unroll
    for (int st = 0; st < 8; ++st) {
      const int d0 = 16 * st + 8 * hp;
      f32x4 a = *(const f32x4*)(qr + d0);
      f32x4 c = *(const f32x4*)(qr + d0 + 4);
      h8 hi;
#pragma unroll
      for (int j = 0; j < 4; ++j) {
        hi[j] = (_Float16)a[j];
        hi[j + 4] = (_Float16)c[j];
      }
      qa[st] = hi;
    }
  }

  f32x16 oacc[4];  // O^T[32dc + dd(reg,hp)][q=l31]
#pragma unroll
  for (int dc = 0; dc < 4; ++dc)
#pragma unroll
    for (int j = 0; j < 16; ++j) oacc[dc][j] = 0.f;
  f32x16 rsacc;  // rowsum via indicator MFMA (all 16 regs identical)
#pragma unroll
  for (int j = 0; j < 16; ++j) rsacc[j] = 0.f;

  const unsigned char* kib = kimg + (size_t)b * 16 * 32768;
  const unsigned char* vib = vimg + (size_t)b * 16 * 32768;
  unsigned char* sind = smem + 131072;

  // ---- prologue: stage tile 0 + whole-batch indicator ----
#pragma unroll
  for (int i = 0; i < 4; ++i) {
    const int off = wv * 4096 + i * 1024;
    glds16(kib + off + lane * 16, smem + off);
    glds16(vib + off + lane * 16, smem + 32768 + off);
  }
  if (wv < 4)
    glds16((const unsigned char*)indg + (size_t)b * 4096 + wv * 1024 + lane * 16,
           sind + wv * 1024);
  __syncthreads();

  const int ksw = (l31 & 7) << 4;  // K row swizzle (key&7 == l31&7)

  for (int tn = 0; tn < NT; ++tn) {
    const unsigned char* kbuf = smem + (tn & 1) * 65536;
    const unsigned char* vbuf = kbuf + 32768;
    if (tn + 1 < NT) {
      unsigned char* nbuf = smem + ((tn + 1) & 1) * 65536;
      const unsigned char* ks = kib + (size_t)(tn + 1) * 32768;
      const unsigned char* vs = vib + (size_t)(tn + 1) * 32768;
#pragma unroll
      for (int i = 0; i < 4; ++i) {
        const int off = wv * 4096 + i * 1024;
        glds16(ks + off + lane * 16, nbuf + off);
        glds16(vs + off + lane * 16, nbuf + 32768 + off);
      }
    }

#pragma unroll
    for (int c = 0; c < 2; ++c) {
      // ---- QK^T swapped (32 keys x 32 q): S[key'][q=l31] ----
      f32x16 s;
#pragma unroll
      for (int j = 0; j < 16; ++j) s[j] = 0.f;
      const int krow = (64 * h + 32 * c + l31) << 8;
      __builtin_amdgcn_s_setprio(1);
#pragma unroll
      for (int st = 0; st < 8; ++st) {
        h8 kf = *(const h8*)(kbuf + krow + ((32 * st + 16 * hp) ^ ksw));
        s = MFMA32(kf, qa[st], s);
      }
      __builtin_amdgcn_s_setprio(0);

      // ---- maskless clipped softmax (Cc = const; C1 pre-folded) ----
      unsigned pkA[4], pkB[4];
#pragma unroll
      for (int jq = 0; jq < 4; ++jq) {
        float p[4];
#pragma unroll
        for (int i = 0; i < 4; ++i) {
          const float u = __builtin_amdgcn_exp2f(s[4 * jq + i]);
          p[i] = __builtin_amdgcn_exp2f(
              fmaf(-C2, __builtin_amdgcn_rcpf(u + 1.0f), CVALID));
        }
        pkA[jq] = __builtin_bit_cast(unsigned,
                                     __builtin_amdgcn_cvt_pkrtz(p[0], p[1]));
        pkB[jq] = __builtin_bit_cast(unsigned,
                                     __builtin_amdgcn_cvt_pkrtz(p[2], p[3]));
      }
      h8 pb[2];  // B-frags, keys 64h+32c+16ks+8hp+j
#pragma unroll
      for (int ks = 0; ks < 2; ++ks) {
        u32x2 sa = __builtin_amdgcn_permlane32_swap(pkA[2 * ks],
                                                    pkA[2 * ks + 1], false,
                                                    false);
        u32x2 sb = __builtin_amdgcn_permlane32_swap(pkB[2 * ks],
                                                    pkB[2 * ks + 1], false,
                                                    false);
        u32x4 w = {sa[0], sb[0], sa[1], sb[1]};
        pb[ks] = __builtin_bit_cast(h8, w);
      }

      // ---- rowsum (indicator) + P.V into persistent C regs ----
      __builtin_amdgcn_s_setprio(1);
#pragma unroll
      for (int ks = 0; ks < 2; ++ks) {
        const int gks = 2 * c + ks;
        h8 ia = *(const h8*)(sind + tn * 256 + 128 * h + 32 * gks + 16 * hp);
        rsacc = MFMA32(ia, pb[ks], rsacc);
      }
#pragma unroll
      for (int dc = 0; dc < 4; ++dc) {
        const int vrow = (32 * dc + l31) << 8;
#pragma unroll
        for (int ks = 0; ks < 2; ++ks) {
          const int gks = 2 * c + ks;
          h8 vf = *(const h8*)(vbuf + vrow +
                               ((128 * h + 32 * gks + 16 * hp) ^ ksw));
          oacc[dc] = MFMA32(vf, pb[ks], oacc[dc]);
        }
      }
      __builtin_amdgcn_s_setprio(0);
    }
    __syncthreads();  // next tile resident; this buf free
  }

  const float totH = rsacc[0];  // all regs identical

  // ---- epilogue: merge key-halves in swizzled LDS, normalize, store ----
  float* rs1 = (float*)(smem + 135168);
  unsigned char* olds = smem;  // f32[128][128], granule ^= (row&31)<<4
  const int row = qg * 32 + l31;
  if (h == 1) {
#pragma unroll
    for (int dc = 0; dc < 4; ++dc)
#pragma unroll
      for (int jq = 0; jq < 4; ++jq) {
        f32x4 v = {oacc[dc][4 * jq + 0], oacc[dc][4 * jq + 1],
                   oacc[dc][4 * jq + 2], oacc[dc][4 * jq + 3]};
        const int dbyte = (32 * dc + 8 * jq + 4 * hp) * 4;
        *(f32x4*)(olds + row * 512 + (dbyte ^ ((row & 31) << 4))) = v;
      }
    if (hp == 0) rs1[row] = totH;
  }
  __syncthreads();
  if (h == 0) {
    const float inv = __builtin_amdgcn_rcpf(totH + rs1[row]);
#pragma unroll
    for (int dc = 0; dc < 4; ++dc)
#pragma unroll
      for (int jq = 0; jq < 4; ++jq) {
        const int dbyte = (32 * dc + 8 * jq + 4 * hp) * 4;
        float* pp = (float*)(olds + row * 512 + (dbyte ^ ((row & 31) << 4)));
        f32x4 v = *(const f32x4*)pp;
        v[0] = (v[0] + oacc[dc][4 * jq + 0]) * inv;
        v[1] = (v[1] + oacc[dc][4 * jq + 1]) * inv;
        v[2] = (v[2] + oacc[dc][4 * jq + 2]) * inv;
        v[3] = (v[3] + oacc[dc][4 * jq + 3]) * inv;
        *(f32x4*)pp = v;
      }
  }
  __syncthreads();
  float* ob = out + ((size_t)b * MM + mt * 128) * DD;
#pragma unroll
  for (int it = 0; it < 8; ++it) {
    const int byte = it * 8192 + tid * 16;
    const int r2 = byte >> 9;
    const int g16 = byte & 511;
    *(f32x4*)((unsigned char*)ob + byte) =
        *(const f32x4*)(olds + r2 * 512 + (g16 ^ ((r2 & 31) << 4)));
  }
}

// ---------------- fallback (round-3 path) if ws too small ----------------
__global__ __launch_bounds__(256, 2) void attn_fallback(
    const float* __restrict__ Qg, const float* __restrict__ Kg,
    const float* __restrict__ Vg, const float* __restrict__ biasC,
    float* __restrict__ out) {
  __shared__ __align__(16) unsigned char smem[51456];
  const int tid = threadIdx.x;
  const int lane = tid & 63;
  const int wv = tid >> 6;
  const int r = lane & 15;
  const int g = lane >> 4;
  const int rw = wv >> 1;
  const int h = wv & 1;
  const int b = blockIdx.x >> 5;
  const int mt = blockIdx.x & 31;
  const int m0 = mt * 64 + rw * 32;

  float* blds = (float*)(smem + 43264);
  {
    const float* cb = biasC + b * NN;
#pragma unroll
    for (int i = 0; i < 8; ++i) blds[tid + 256 * i] = cb[tid + 256 * i];
  }
  h8 qh[2][4];
  {
    const float* qb = Qg + ((size_t)b * MM + m0) * DD;
#pragma unroll
    for (int rf = 0; rf < 2; ++rf) {
      const float* qr = qb + (16 * rf + r) * DD;
#pragma unroll
      for (int t = 0; t < 4; ++t) {
        f32x4 a = *(const f32x4*)(qr + 32 * t + 8 * g);
        f32x4 c = *(const f32x4*)(qr + 32 * t + 8 * g + 4);
        h8 hi;
#pragma unroll
        for (int j = 0; j < 4; ++j) {
          hi[j] = (_Float16)a[j];
          hi[j + 4] = (_Float16)c[j];
        }
        qh[rf][t] = hi;
      }
    }
  }
  f32x4 acc[2][8];
#pragma unroll
  for (int rf = 0; rf < 2; ++rf)
#pragma unroll
    for (int cd = 0; cd < 8; ++cd) acc[rf][cd] = (f32x4){0.f, 0.f, 0.f, 0.f};
  float rs[2][4] = {{0.f, 0.f, 0.f, 0.f}, {0.f, 0.f, 0.f, 0.f}};
  const float* kb = Kg + (size_t)b * NN * DD;
  const float* vbp = Vg + (size_t)b * NN * DD;
  _Float16* plds = (_Float16*)(smem + 32768 + wv * 2560);
  const int bk0 = tid >> 5, bd0 = tid & 31;
  const int bk1 = (256 + tid) >> 5, bd1 = tid & 31;
  f32x4 kpre[8], vpre[8];
#pragma unroll
  for (int i = 0; i < 8; ++i) kpre[i] = *(const f32x4*)(kb + i * 1024 + tid * 4);
#pragma unroll
  for (int q = 0; q < 4; ++q) {
    vpre[q] = *(const f32x4*)(vbp + (4 * bk0 + q) * DD + 4 * bd0);
    vpre[4 + q] = *(const f32x4*)(vbp + (4 * bk1 + q) * DD + 4 * bd1);
  }
  for (int tn = 0; tn < 32; ++tn) {
#pragma unroll
    for (int i = 0; i < 8; ++i) {
      const int flat = i * 1024 + tid * 4;
      const int kkey = flat >> 7;
      const int d0 = flat & 127;
      h4 hv;
#pragma unroll
      for (int j = 0; j < 4; ++j) hv[j] = (_Float16)kpre[i][j];
      *(h4*)(smem + (kkey << 8) + ((d0 << 1) ^ ((kkey & 7) << 4))) = hv;
    }
#pragma unroll
    for (int it = 0; it < 2; ++it) {
      const int bk = it ? bk1 : bk0;
      const int bd = it ? bd1 : bd0;
#pragma unroll
      for (int p = 0; p < 4; ++p) {
        h4 w;
#pragma unroll
        for (int q = 0; q < 4; ++q) w[q] = (_Float16)vpre[it * 4 + q][p];
        const int d = 4 * bd + p;
        *(h4*)(smem + 16384 + (d << 7) +
               ((bk << 3) ^ (((d >> 1) & 7) << 4))) = w;
      }
    }
    if (tn + 1 < 32) {
      const float* ks = kb + (tn + 1) * 64 * DD;
      const float* vs = vbp + (tn + 1) * 64 * DD;
#pragma unroll
      for (int i = 0; i < 8; ++i) kpre[i] = *(const f32x4*)(ks + i * 1024 + tid * 4);
#pragma unroll
      for (int q = 0; q < 4; ++q) {
        vpre[q] = *(const f32x4*)(vs + (4 * bk0 + q) * DD + 4 * bd0);
        vpre[4 + q] = *(const f32x4*)(vs + (4 * bk1 + q) * DD + 4 * bd1);
      }
    }
    __syncthreads();
#pragma unroll
    for (int c = 0; c < 2; ++c) {
      f32x4 S0 = {0.f, 0.f, 0.f, 0.f}, S1 = {0.f, 0.f, 0.f, 0.f};
      const int kkey = h * 32 + 16 * c + r;
      const int krow = kkey << 8;
      const int ksw = (kkey & 7) << 4;
#pragma unroll
      for (int t = 0; t < 4; ++t) {
        h8 kf = *(const h8*)(smem + krow + ((64 * t + 16 * g) ^ ksw));
        S0 = MFMA16(qh[0][t], kf, S0);
        S1 = MFMA16(qh[1][t], kf, S1);
      }
      const float Cc = blds[tn * 64 + kkey];
#pragma unroll
      for (int j = 0; j < 4; ++j) {
        float u0 = __builtin_amdgcn_exp2f(S0[j] * C1);
        float p0 = __builtin_amdgcn_exp2f(
            fmaf(-C2, __builtin_amdgcn_rcpf(u0 + 1.0f), Cc));
        rs[0][j] += p0;
        plds[(4 * g + j) * 40 + 16 * c + r] = (_Float16)p0;
        float u1 = __builtin_amdgcn_exp2f(S1[j] * C1);
        float p1 = __builtin_amdgcn_exp2f(
            fmaf(-C2, __builtin_amdgcn_rcpf(u1 + 1.0f), Cc));
        rs[1][j] += p1;
        plds[(16 + 4 * g + j) * 40 + 16 * c + r] = (_Float16)p1;
      }
    }
    h8 a0 = *(const h8*)((unsigned char*)plds + r * 80 + 16 * g);
    h8 a1 = *(const h8*)((unsigned char*)plds + (16 + r) * 80 + 16 * g);
#pragma unroll
    for (int cd = 0; cd < 8; ++cd) {
      const int d = 16 * cd + r;
      h8 vf = *(const h8*)(smem + 16384 + (d << 7) +
                           ((64 * h + 16 * g) ^ (((d >> 1) & 7) << 4)));
      acc[0][cd] = MFMA16(a0, vf, acc[0][cd]);
      acc[1][cd] = MFMA16(a1, vf, acc[1][cd]);
    }
    __syncthreads();
  }
#pragma unroll
  for (int rf = 0; rf < 2; ++rf)
#pragma unroll
    for (int j = 0; j < 4; ++j) {
      float v = rs[rf][j];
      v += __shfl_xor(v, 1);
      v += __shfl_xor(v, 2);
      v += __shfl_xor(v, 4);
      v += __shfl_xor(v, 8);
      rs[rf][j] = v;
    }
  float* olds = (float*)smem;
  float* rslds = (float*)(smem + 43008);
  if (h == 1) {
    float* my = olds + rw * 4096;
#pragma unroll
    for (int rf = 0; rf < 2; ++rf)
#pragma unroll
      for (int cd = 0; cd < 8; ++cd)
#pragma unroll
        for (int j = 0; j < 4; ++j)
          my[(16 * rf + 4 * g + j) * 128 + 16 * cd + r] = acc[rf][cd][j];
    if (r == 0) {
#pragma unroll
      for (int rf = 0; rf < 2; ++rf)
#pragma unroll
        for (int j = 0; j < 4; ++j)
          rslds[rw * 32 + 16 * rf + 4 * g + j] = rs[rf][j];
    }
  }
  __syncthreads();
  if (h == 0) {
    const float* ot = olds + rw * 4096;
    float* ob = out + ((size_t)b * MM + m0) * DD;
#pragma unroll
    for (int rf = 0; rf < 2; ++rf)
#pragma unroll
      for (int j = 0; j < 4; ++j) {
        const int rl = 16 * rf + 4 * g + j;
        const float tot = rs[rf][j] + rslds[rw * 32 + rl];
        const float inv = __builtin_amdgcn_rcpf(tot);
#pragma unroll
        for (int cd = 0; cd < 8; ++cd) {
          float v = acc[rf][cd][j] + ot[rl * 128 + 16 * cd + r];
          ob[rl * DD + 16 * cd + r] = v * inv;
        }
      }
  }
}

extern "C" void kernel_launch(void* const* d_in, const int* in_sizes, int n_in,
                              void* d_out, int out_size, void* d_ws, size_t ws_size,
                              hipStream_t stream) {
  const float* Q = (const float*)d_in[0];
  const float* K = (const float*)d_in[1];
  const float* V = (const float*)d_in[2];
  const void* mask = d_in[3];
  float* out = (float*)d_out;
  if (ws_size >= WS_NEED) {
    unsigned char* kimg = (unsigned char*)d_ws;
    unsigned char* vimg = kimg + KV_IMG;
    _Float16* ind = (_Float16*)(vimg + KV_IMG);
    prep_all<<<dim3(1024), dim3(256), 0, stream>>>(K, V, mask, kimg, vimg, ind);
    attn_main<<<dim3(256), dim3(512), 0, stream>>>(Q, kimg, vimg, ind, out);
  } else {
    float* biasC = (float*)d_ws;  // 32768 floats
    prep_bias<<<dim3(128), dim3(256), 0, stream>>>(mask, biasC);
    attn_fallback<<<dim3(512), dim3(256), 0, stream>>>(Q, K, V, biasC, out);
  }
}